// Round 5
// baseline (861.774 us; speedup 1.0000x reference)
//
#include <hip/hip_runtime.h>
#include <hip/hip_bf16.h>
#include <cstdint>
#include <cstddef>

// ---------------------------------------------------------------------------
// MeshDecoder pipeline, round 5.
// bf16 activations (B,E,C). MFMA convs M-blocked (MT tiles/wave) for gather
// memory-level parallelism. Stats fused into conv epilogues; LDS-tiled unpool.
// ---------------------------------------------------------------------------

typedef short s16x8 __attribute__((ext_vector_type(8)));
typedef unsigned short u16x8 __attribute__((ext_vector_type(8)));
typedef float f32x4 __attribute__((ext_vector_type(4)));

__device__ __forceinline__ float bfbits2f(unsigned short u) {
    unsigned int x = ((unsigned int)u) << 16;
    float f; __builtin_memcpy(&f, &x, sizeof(f)); return f;
}
__device__ __forceinline__ unsigned short f2bfbits(float f) {
    __hip_bfloat16 h = __float2bfloat16(f);
    unsigned short u; __builtin_memcpy(&u, &h, sizeof(u)); return u;
}

// (B,C,E) fp32 -> (B,E,C) bf16 tiled transpose
__global__ __launch_bounds__(256) void k_transpose_in(
    const float* __restrict__ in, unsigned short* __restrict__ out, int C, int E)
{
    __shared__ float tile[64][65];
    const int e0 = blockIdx.x * 64;
    const int c0 = blockIdx.y * 64;
    const int b  = blockIdx.z;
    const float* inb = in + (size_t)b * C * E;
    const int l = threadIdx.x % 64;
    const int g = threadIdx.x / 64;
#pragma unroll
    for (int i = 0; i < 16; ++i) {
        const int c = i * 4 + g;
        tile[c][l] = inb[(size_t)(c0 + c) * E + e0 + l];
    }
    __syncthreads();
    unsigned short* outb = out + (size_t)b * E * C;
#pragma unroll
    for (int i = 0; i < 16; ++i) {
        const int e = i * 4 + g;
        outb[(size_t)(e0 + e) * C + c0 + l] = f2bfbits(tile[l][e]);
    }
}

// W (O,C,5) fp32 -> B-fragment-packed bf16: Bp[((kk*O)+o)*8 + j], k=kk*8+j=s*C+c
__global__ __launch_bounds__(256) void k_prep_b(
    const float* __restrict__ W, unsigned short* __restrict__ Bp, int C, int O)
{
    const int p = blockIdx.x * 256 + threadIdx.x;
    const int total = 5 * C * O;
    if (p >= total) return;
    const int j = p & 7;
    const int t = p >> 3;
    const int o = t % O;
    const int kk = t / O;
    const int k = kk * 8 + j;
    const int s = k / C;
    const int c = k - s * C;
    Bp[p] = f2bfbits(W[((size_t)o * C + c) * 5 + s]);
}

// W (O,C,5) fp32 -> W_T[(c*5+s)*O + o] fp32 (VALU-path weights)
__global__ __launch_bounds__(256) void k_prep_w(
    const float* __restrict__ W, float* __restrict__ Wt, int C, int O)
{
    const int idx = blockIdx.x * 256 + threadIdx.x;
    const int total = C * 5 * O;
    if (idx >= total) return;
    const int k = idx / O;
    const int o = idx % O;
    const int c = k / 5;
    const int s = k - 5 * c;
    Wt[idx] = W[((size_t)o * C + c) * 5 + s];
}

// MFMA mesh_conv, MT M-tiles per wave, optional fused per-channel stats.
template<int C, int O, int MT, bool STATS>
__global__ __launch_bounds__(256) void k_conv_mfma(
    const unsigned short* __restrict__ x, const int* __restrict__ gm,
    const unsigned short* __restrict__ Bp, const float* __restrict__ bias,
    unsigned short* __restrict__ out, float* __restrict__ stats, int E)
{
    constexpr int NT  = O / 16;
    constexpr int ITS = C / 32;
    static_assert(C % 32 == 0 && O % 16 == 0, "bad cfg");
    const int tid  = threadIdx.x;
    const int wave = tid >> 6;
    const int lane = tid & 63;
    const int m    = lane & 15;
    const int kq   = lane >> 4;
    const int b    = blockIdx.y;
    const int e0   = (blockIdx.x * 4 + wave) * (16 * MT);
    const unsigned short* xb = x + (size_t)b * E * C;

    int roff[MT][5];
#pragma unroll
    for (int mt = 0; mt < MT; ++mt) {
        const int e = e0 + mt * 16 + m;
        const int4 gi = *reinterpret_cast<const int4*>(gm + 4 * (size_t)e);
        roff[mt][0] = e * C;
        roff[mt][1] = gi.x * C;
        roff[mt][2] = gi.y * C;
        roff[mt][3] = gi.z * C;
        roff[mt][4] = gi.w * C;
    }

    const s16x8* Bp8 = reinterpret_cast<const s16x8*>(Bp);

    f32x4 acc[MT][NT];
#pragma unroll
    for (int mt = 0; mt < MT; ++mt)
#pragma unroll
        for (int nt = 0; nt < NT; ++nt) acc[mt][nt] = (f32x4){0.f, 0.f, 0.f, 0.f};

#pragma unroll
    for (int s = 0; s < 5; ++s) {
#pragma unroll
        for (int it = 0; it < ITS; ++it) {
            const int c0 = it * 32 + kq * 8;
            s16x8 afrag[MT];
#pragma unroll
            for (int mt = 0; mt < MT; ++mt) {
                if (s == 0) {
                    afrag[mt] = *reinterpret_cast<const s16x8*>(xb + roff[mt][0] + c0);
                } else {
                    constexpr int dummy = 0; (void)dummy;
                    const int ia = (s == 1 || s == 3) ? 1 : 2;
                    const s16x8 av = *reinterpret_cast<const s16x8*>(xb + roff[mt][ia] + c0);
                    const s16x8 bv = *reinterpret_cast<const s16x8*>(xb + roff[mt][ia + 2] + c0);
#pragma unroll
                    for (int j = 0; j < 8; ++j) {
                        const float fa = bfbits2f((unsigned short)av[j]);
                        const float fb = bfbits2f((unsigned short)bv[j]);
                        const float t = (s < 3) ? (fa + fb) : fabsf(fa - fb);
                        afrag[mt][j] = (short)f2bfbits(t);
                    }
                }
            }
            const int kk = s * (C / 8) + it * 4 + kq;
#pragma unroll
            for (int nt = 0; nt < NT; ++nt) {
                const s16x8 bfrag = Bp8[(size_t)kk * O + nt * 16 + m];
#pragma unroll
                for (int mt = 0; mt < MT; ++mt)
                    acc[mt][nt] = __builtin_amdgcn_mfma_f32_16x16x32_bf16(afrag[mt], bfrag, acc[mt][nt], 0, 0, 0);
            }
        }
    }

    float ssum[NT], ssq[NT];
#pragma unroll
    for (int nt = 0; nt < NT; ++nt) { ssum[nt] = 0.f; ssq[nt] = 0.f; }

#pragma unroll
    for (int mt = 0; mt < MT; ++mt) {
        const int ebase = e0 + mt * 16 + kq * 4;
#pragma unroll
        for (int nt = 0; nt < NT; ++nt) {
            const int o = nt * 16 + m;
            const float bo = bias[o];
#pragma unroll
            for (int r = 0; r < 4; ++r) {
                const float z = acc[mt][nt][r] + bo;
                out[((size_t)b * E + (ebase + r)) * O + o] = f2bfbits(z);
                ssum[nt] += z; ssq[nt] += z * z;
            }
        }
    }

    if constexpr (STATS) {
        __shared__ float ls[4][2][O];
#pragma unroll
        for (int nt = 0; nt < NT; ++nt) {
            float s = ssum[nt], q = ssq[nt];
            s += __shfl_xor(s, 16); s += __shfl_xor(s, 32);
            q += __shfl_xor(q, 16); q += __shfl_xor(q, 32);
            if (kq == 0) { ls[wave][0][nt * 16 + m] = s; ls[wave][1][nt * 16 + m] = q; }
        }
        __syncthreads();
        if (tid < O) {
            const float S = ls[0][0][tid] + ls[1][0][tid] + ls[2][0][tid] + ls[3][0][tid];
            const float Q = ls[0][1][tid] + ls[1][1][tid] + ls[2][1][tid] + ls[3][1][tid];
            atomicAdd(&stats[((size_t)b * O + tid) * 2], S);
            atomicAdd(&stats[((size_t)b * O + tid) * 2 + 1], Q);
        }
    }
}

// VALU mesh_conv for O=8: one e per thread, 16B row loads.
template<int C, int O, bool STATS>
__global__ __launch_bounds__(256) void k_conv_small(
    const unsigned short* __restrict__ x, const int* __restrict__ gm,
    const float* __restrict__ Wt, const float* __restrict__ bias,
    unsigned short* __restrict__ out, float* __restrict__ stats, int E)
{
    static_assert(O == 8 && C % 8 == 0, "bad cfg");
    __shared__ float ls[2 * O];
    const int tid = threadIdx.x;
    if constexpr (STATS) {
        if (tid < 2 * O) ls[tid] = 0.f;
        __syncthreads();
    }
    const int b = blockIdx.y;
    const int e = blockIdx.x * 256 + tid;
    const unsigned short* xb = x + (size_t)b * E * C;
    const int4 gi = *reinterpret_cast<const int4*>(gm + 4 * (size_t)e);
    const unsigned short* rp[5] = {
        xb + (size_t)e * C, xb + (size_t)gi.x * C, xb + (size_t)gi.y * C,
        xb + (size_t)gi.z * C, xb + (size_t)gi.w * C };

    float acc[O];
#pragma unroll
    for (int o = 0; o < O; ++o) acc[o] = bias[o];

#pragma unroll
    for (int c = 0; c < C; c += 8) {
        u16x8 rv[5];
#pragma unroll
        for (int k = 0; k < 5; ++k) rv[k] = *reinterpret_cast<const u16x8*>(rp[k] + c);
#pragma unroll
        for (int cc = 0; cc < 8; ++cc) {
            const float x0 = bfbits2f(rv[0][cc]);
            const float f1 = bfbits2f(rv[1][cc]);
            const float f2 = bfbits2f(rv[2][cc]);
            const float f3 = bfbits2f(rv[3][cc]);
            const float f4 = bfbits2f(rv[4][cc]);
            const float gv[5] = { x0, f1 + f3, f2 + f4, fabsf(f1 - f3), fabsf(f2 - f4) };
            const float* wbase = Wt + (size_t)(c + cc) * 5 * O;
#pragma unroll
            for (int s = 0; s < 5; ++s)
#pragma unroll
                for (int o = 0; o < O; ++o)
                    acc[o] += gv[s] * wbase[s * O + o];
        }
    }

    u16x8 ov;
#pragma unroll
    for (int o = 0; o < O; ++o) ov[o] = f2bfbits(acc[o]);
    *reinterpret_cast<u16x8*>(out + ((size_t)b * E + e) * O) = ov;

    if constexpr (STATS) {
#pragma unroll
        for (int o = 0; o < O; ++o) {
            atomicAdd(&ls[o * 2], acc[o]);
            atomicAdd(&ls[o * 2 + 1], acc[o] * acc[o]);
        }
        __syncthreads();
        if (tid < 2 * O) atomicAdd(&stats[(size_t)b * 2 * O + tid], ls[tid]);
    }
}

// x1[b,e,o] = y[b, up[e], o] + skip[b, o, e]  -- LDS-tiled (coalesced skip reads)
template<int O>
__global__ __launch_bounds__(256) void k_unpool_skip(
    const unsigned short* __restrict__ y, const int* __restrict__ up,
    const float* __restrict__ skip, unsigned short* __restrict__ out,
    int Ein, int Eout)
{
    __shared__ float sk[O][65];
    const int b  = blockIdx.y;
    const int e0 = blockIdx.x * 64;
    const int t  = threadIdx.x;
    constexpr int L = O / 16;   // float4 loads per thread
#pragma unroll
    for (int i = 0; i < L; ++i) {
        const int flat = i * 256 + t;
        const int o = flat >> 4;
        const int el4 = (flat & 15) * 4;
        const float4 v = *reinterpret_cast<const float4*>(
            skip + ((size_t)b * O + o) * Eout + e0 + el4);
        sk[o][el4]     = v.x;
        sk[o][el4 + 1] = v.y;
        sk[o][el4 + 2] = v.z;
        sk[o][el4 + 3] = v.w;
    }
    __syncthreads();
    constexpr int OG  = O / 4;       // threads per e
    constexpr int EPP = 256 / OG;    // e's per pass
    const int o4  = (t % OG) * 4;
    const int elg = t / OG;
#pragma unroll
    for (int p = 0; p < 64 / EPP; ++p) {
        const int el = p * EPP + elg;
        const int e  = e0 + el;
        const int u  = up[e];
        const ushort4 yv = *reinterpret_cast<const ushort4*>(
            y + ((size_t)b * Ein + u) * O + o4);
        ushort4 ov;
        ov.x = f2bfbits(bfbits2f(yv.x) + sk[o4 + 0][el]);
        ov.y = f2bfbits(bfbits2f(yv.y) + sk[o4 + 1][el]);
        ov.z = f2bfbits(bfbits2f(yv.z) + sk[o4 + 2][el]);
        ov.w = f2bfbits(bfbits2f(yv.w) + sk[o4 + 3][el]);
        *reinterpret_cast<ushort4*>(out + ((size_t)b * Eout + e) * O + o4) = ov;
    }
}

// stats -> scale/shift
__global__ __launch_bounds__(256) void k_scale(
    const float* __restrict__ stats, float* __restrict__ ss, int BC, float invE)
{
    const int t = threadIdx.x;
    if (t < BC) {
        const float sum = stats[t * 2];
        const float sq  = stats[t * 2 + 1];
        const float m   = sum * invE;
        const float var = fmaxf(sq * invE - m * m, 0.f);
        const float sc  = rsqrtf(var + 1e-5f);
        ss[t * 2] = sc;
        ss[t * 2 + 1] = -m * sc;
    }
}

// in-place relu((x)*sc + sh), vectorized ushort8
template<int C>
__global__ __launch_bounds__(256) void k_norm_relu(
    unsigned short* __restrict__ x, const float* __restrict__ ss, int E)
{
    const int b = blockIdx.y;
    const size_t i8 = ((size_t)blockIdx.x * 256 + threadIdx.x) * 8;
    const int c0 = (int)(i8 % C);
    unsigned short* p = x + (size_t)b * E * C + i8;
    const u16x8 v = *reinterpret_cast<const u16x8*>(p);
    u16x8 r;
#pragma unroll
    for (int j = 0; j < 8; ++j) {
        const float sc = ss[(b * C + c0 + j) * 2];
        const float sh = ss[(b * C + c0 + j) * 2 + 1];
        r[j] = f2bfbits(fmaxf(bfbits2f(v[j]) * sc + sh, 0.f));
    }
    *reinterpret_cast<u16x8*>(p) = r;
}

// final: (B,E,8) bf16 -> norm+relu -> (B,8,E) fp32
__global__ __launch_bounds__(256) void k_final_out(
    const unsigned short* __restrict__ z, const float* __restrict__ ss,
    float* __restrict__ out, int E)
{
    const int b = blockIdx.y;
    const int idx = blockIdx.x * 256 + threadIdx.x;  // over 8*E
    const int o = idx / E;
    const int e = idx % E;
    const float sc = ss[((size_t)b * 8 + o) * 2];
    const float sh = ss[((size_t)b * 8 + o) * 2 + 1];
    const float v = bfbits2f(z[((size_t)b * E + e) * 8 + o]) * sc + sh;
    out[(size_t)b * 8 * E + idx] = fmaxf(v, 0.f);
}

extern "C" void kernel_launch(void* const* d_in, const int* in_sizes, int n_in,
                              void* d_out, int out_size, void* d_ws, size_t ws_size,
                              hipStream_t stream)
{
    (void)in_sizes; (void)n_in; (void)out_size; (void)ws_size;

    const float* fe = (const float*)d_in[0];
    const int* gemm0 = (const int*)d_in[4];
    const int* gemm1 = (const int*)d_in[5];
    const int* gemm2 = (const int*)d_in[6];
    const int* gemm3 = (const int*)d_in[7];
    const int* up0 = (const int*)d_in[8];
    const int* up1 = (const int*)d_in[9];
    const int* up2 = (const int*)d_in[10];
    const float* bup0 = (const float*)d_in[12];
    const float* bc0  = (const float*)d_in[14];
    const float* bup1 = (const float*)d_in[16];
    const float* bc1  = (const float*)d_in[18];
    const float* bup2 = (const float*)d_in[20];
    const float* bc2  = (const float*)d_in[22];
    const float* bupf = (const float*)d_in[24];
    const float* bcf  = (const float*)d_in[26];

    unsigned short* wsb = (unsigned short*)d_ws;
    const size_t NP = 8388608;  // 2*32768*128 = max activation elems
    unsigned short* P0 = wsb;
    unsigned short* P1 = wsb + NP;
    unsigned short* P2 = wsb + 2 * NP;
    unsigned short* Bp_up0 = wsb + 3 * NP;       // 5*256*128 = 163840
    unsigned short* Bp_c0  = Bp_up0 + 163840;    // 5*128*128 =  81920
    unsigned short* Bp_up1 = Bp_c0  + 81920;     // 5*128*64  =  40960
    unsigned short* Bp_c1  = Bp_up1 + 40960;     // 5*64*64   =  20480
    unsigned short* Bp_up2 = Bp_c1  + 20480;     // 5*64*32   =  10240
    unsigned short* Bp_c2  = Bp_up2 + 10240;     // 5*32*32   =   5120
    float* fls    = (float*)(Bp_c2 + 5120);
    float* wt_upf = fls;                  // 32*5*8 = 1280
    float* wt_cf  = wt_upf + 1280;        //  8*5*8 =  320
    float* stats0 = wt_cf  + 320;         // 2*128*2 = 512
    float* stats1 = stats0 + 512;         // 2*64*2  = 256
    float* stats2 = stats1 + 256;         // 2*32*2  = 128
    float* stats3 = stats2 + 128;         // 2*8*2   = 32
    float* ss0    = stats3 + 32;
    float* ss1    = ss0 + 512;
    float* ss2    = ss1 + 256;
    float* ss3    = ss2 + 128;

    hipMemsetAsync(stats0, 0, 928 * sizeof(float), stream);

    const dim3 blk(256);

    // input transpose: fe (2,256,16384) fp32 -> P0 (2,16384,256) bf16
    k_transpose_in<<<dim3(16384 / 64, 256 / 64, 2), blk, 0, stream>>>(fe, P0, 256, 16384);

    // weight packing
    k_prep_b<<<dim3(163840 / 256), blk, 0, stream>>>((const float*)d_in[11], Bp_up0, 256, 128);
    k_prep_b<<<dim3(81920 / 256),  blk, 0, stream>>>((const float*)d_in[13], Bp_c0, 128, 128);
    k_prep_b<<<dim3(40960 / 256),  blk, 0, stream>>>((const float*)d_in[15], Bp_up1, 128, 64);
    k_prep_b<<<dim3(20480 / 256),  blk, 0, stream>>>((const float*)d_in[17], Bp_c1, 64, 64);
    k_prep_b<<<dim3(10240 / 256),  blk, 0, stream>>>((const float*)d_in[19], Bp_up2, 64, 32);
    k_prep_b<<<dim3(5120 / 256),   blk, 0, stream>>>((const float*)d_in[21], Bp_c2, 32, 32);
    k_prep_w<<<dim3((1280 + 255) / 256), blk, 0, stream>>>((const float*)d_in[23], wt_upf, 32, 8);
    k_prep_w<<<dim3((320 + 255) / 256),  blk, 0, stream>>>((const float*)d_in[25], wt_cf, 8, 8);

    // ---- stage 0 ----
    k_conv_mfma<256, 128, 1, false><<<dim3(16384 / 64, 2), blk, 0, stream>>>(P0, gemm0, Bp_up0, bup0, P1, nullptr, 16384);
    k_unpool_skip<128><<<dim3(32768 / 64, 2), blk, 0, stream>>>(P1, up0, (const float*)d_in[1], P2, 16384, 32768);
    k_conv_mfma<128, 128, 2, true><<<dim3(32768 / 128, 2), blk, 0, stream>>>(P2, gemm1, Bp_c0, bc0, P0, stats0, 32768);
    k_scale<<<dim3(1), blk, 0, stream>>>(stats0, ss0, 256, 1.f / 32768.f);
    k_norm_relu<128><<<dim3(32768 * 128 / 2048, 2), blk, 0, stream>>>(P0, ss0, 32768);

    // ---- stage 1 ----
    k_conv_mfma<128, 64, 2, false><<<dim3(32768 / 128, 2), blk, 0, stream>>>(P0, gemm1, Bp_up1, bup1, P1, nullptr, 32768);
    k_unpool_skip<64><<<dim3(65536 / 64, 2), blk, 0, stream>>>(P1, up1, (const float*)d_in[2], P2, 32768, 65536);
    k_conv_mfma<64, 64, 4, true><<<dim3(65536 / 256, 2), blk, 0, stream>>>(P2, gemm2, Bp_c1, bc1, P0, stats1, 65536);
    k_scale<<<dim3(1), blk, 0, stream>>>(stats1, ss1, 128, 1.f / 65536.f);
    k_norm_relu<64><<<dim3(65536 * 64 / 2048, 2), blk, 0, stream>>>(P0, ss1, 65536);

    // ---- stage 2 ----
    k_conv_mfma<64, 32, 4, false><<<dim3(65536 / 256, 2), blk, 0, stream>>>(P0, gemm2, Bp_up2, bup2, P1, nullptr, 65536);
    k_unpool_skip<32><<<dim3(131072 / 64, 2), blk, 0, stream>>>(P1, up2, (const float*)d_in[3], P2, 65536, 131072);
    k_conv_mfma<32, 32, 4, true><<<dim3(131072 / 256, 2), blk, 0, stream>>>(P2, gemm3, Bp_c2, bc2, P0, stats2, 131072);
    k_scale<<<dim3(1), blk, 0, stream>>>(stats2, ss2, 64, 1.f / 131072.f);
    k_norm_relu<32><<<dim3(131072 * 32 / 2048, 2), blk, 0, stream>>>(P0, ss2, 131072);

    // ---- final ----
    k_conv_small<32, 8, false><<<dim3(131072 / 256, 2), blk, 0, stream>>>(P0, gemm3, wt_upf, bupf, P1, nullptr, 131072);
    k_conv_small<8, 8, true><<<dim3(131072 / 256, 2), blk, 0, stream>>>(P1, gemm3, wt_cf, bcf, P2, stats3, 131072);
    k_scale<<<dim3(1), blk, 0, stream>>>(stats3, ss3, 16, 1.f / 131072.f);
    k_final_out<<<dim3(8 * 131072 / 256, 2), blk, 0, stream>>>(P2, ss3, (float*)d_out, 131072);
}

// Round 6
// 743.074 us; speedup vs baseline: 1.1597x; 1.1597x over previous
//
#include <hip/hip_runtime.h>
#include <hip/hip_bf16.h>
#include <cstdint>
#include <cstddef>

// ---------------------------------------------------------------------------
// MeshDecoder pipeline, round 6.
// bf16 activations (B,E,C). Convs: LDS-staged gather (cooperative, high MLP)
// + dense MFMA from LDS. Stats fused into conv epilogues; LDS-tiled unpool.
// R5 lesson: no register M-blocking (VGPR 164 killed occupancy); MLP comes
// from 256-thread cooperative staging instead.
// ---------------------------------------------------------------------------

typedef short s16x8 __attribute__((ext_vector_type(8)));
typedef unsigned short u16x8 __attribute__((ext_vector_type(8)));
typedef float f32x4 __attribute__((ext_vector_type(4)));

__device__ __forceinline__ float bfbits2f(unsigned short u) {
    unsigned int x = ((unsigned int)u) << 16;
    float f; __builtin_memcpy(&f, &x, sizeof(f)); return f;
}
__device__ __forceinline__ unsigned short f2bfbits(float f) {
    __hip_bfloat16 h = __float2bfloat16(f);
    unsigned short u; __builtin_memcpy(&u, &h, sizeof(u)); return u;
}

// (B,C,E) fp32 -> (B,E,C) bf16 tiled transpose
__global__ __launch_bounds__(256) void k_transpose_in(
    const float* __restrict__ in, unsigned short* __restrict__ out, int C, int E)
{
    __shared__ float tile[64][65];
    const int e0 = blockIdx.x * 64;
    const int c0 = blockIdx.y * 64;
    const int b  = blockIdx.z;
    const float* inb = in + (size_t)b * C * E;
    const int l = threadIdx.x % 64;
    const int g = threadIdx.x / 64;
#pragma unroll
    for (int i = 0; i < 16; ++i) {
        const int c = i * 4 + g;
        tile[c][l] = inb[(size_t)(c0 + c) * E + e0 + l];
    }
    __syncthreads();
    unsigned short* outb = out + (size_t)b * E * C;
#pragma unroll
    for (int i = 0; i < 16; ++i) {
        const int e = i * 4 + g;
        outb[(size_t)(e0 + e) * C + c0 + l] = f2bfbits(tile[l][e]);
    }
}

// W (O,C,5) fp32 -> B-fragment-packed bf16: Bp[((kk*OP)+o)*8 + j], k=kk*8+j=s*C+c
// OP = physical O (may be padded beyond logical OL with zeros).
__global__ __launch_bounds__(256) void k_prep_b(
    const float* __restrict__ W, unsigned short* __restrict__ Bp, int C, int OP, int OL)
{
    const int p = blockIdx.x * 256 + threadIdx.x;
    const int total = 5 * C * OP;
    if (p >= total) return;
    const int j = p & 7;
    const int t = p >> 3;
    const int o = t % OP;
    const int kk = t / OP;
    const int k = kk * 8 + j;
    const int s = k / C;
    const int c = k - s * C;
    Bp[p] = (o < OL) ? f2bfbits(W[((size_t)o * C + c) * 5 + s]) : (unsigned short)0;
}

// W (O,C,5) fp32 -> W_T[(c*5+s)*O + o] fp32 (VALU-path weights)
__global__ __launch_bounds__(256) void k_prep_w(
    const float* __restrict__ W, float* __restrict__ Wt, int C, int O)
{
    const int idx = blockIdx.x * 256 + threadIdx.x;
    const int total = C * 5 * O;
    if (idx >= total) return;
    const int k = idx / O;
    const int o = idx % O;
    const int c = k / 5;
    const int s = k - 5 * c;
    Wt[idx] = W[((size_t)o * C + c) * 5 + s];
}

// LDS-staged MFMA mesh_conv. Block = 64 e-rows, 256 threads (4 waves).
// O = physical output width (multiple of 16); OW = logical (written) width.
template<int C, int O, bool STATS, int OW = O>
__global__ __launch_bounds__(256) void k_conv_mfma(
    const unsigned short* __restrict__ x, const int* __restrict__ gm,
    const unsigned short* __restrict__ Bp, const float* __restrict__ bias,
    unsigned short* __restrict__ out, float* __restrict__ stats, int E)
{
    constexpr int NT    = O / 16;
    constexpr int ITS   = C / 32;        // 16x16x32 k-steps per segment
    constexpr int OCT   = C / 8;         // 16B octets per row per segment
    constexpr int ITERS = (64 * OCT) / 256;
    constexpr int PAD   = 8;             // ushorts; lane stride ≡ 4 banks → 2-way (free)
    constexpr int RW    = C + PAD;
    constexpr bool PAIRED = (C <= 128);
    constexpr int SLOTS = PAIRED ? 2 : 1;
    static_assert(C % 32 == 0 && O % 16 == 0, "bad cfg");

    __shared__ unsigned short smem[SLOTS][64][RW];
    __shared__ int gis[64][4];

    const int tid  = threadIdx.x;
    const int wave = tid >> 6;
    const int lane = tid & 63;
    const int m    = lane & 15;
    const int kq   = lane >> 4;
    const int b    = blockIdx.y;
    const int e0   = blockIdx.x * 64;
    const unsigned short* xb = x + (size_t)b * E * C;
    const s16x8* Bp8 = reinterpret_cast<const s16x8*>(Bp);

    if (tid < 64)
        *reinterpret_cast<int4*>(gis[tid]) =
            *reinterpret_cast<const int4*>(gm + 4 * (size_t)(e0 + tid));

    f32x4 acc[NT];
#pragma unroll
    for (int nt = 0; nt < NT; ++nt) acc[nt] = (f32x4){0.f, 0.f, 0.f, 0.f};

    // ---- MFMA over one staged segment ----
    auto mfma_seg = [&](int slot, int s) {
#pragma unroll
        for (int it = 0; it < ITS; ++it) {
            const s16x8 afrag = *reinterpret_cast<const s16x8*>(
                &smem[slot][wave * 16 + m][it * 32 + kq * 8]);
            const int kkb = s * OCT + it * 4 + kq;
#pragma unroll
            for (int nt = 0; nt < NT; ++nt) {
                const s16x8 bfrag = Bp8[(size_t)kkb * O + nt * 16 + m];
                acc[nt] = __builtin_amdgcn_mfma_f32_16x16x32_bf16(afrag, bfrag, acc[nt], 0, 0, 0);
            }
        }
    };

    // ---- Phase s=0: own rows, no gather ----
#pragma unroll
    for (int i = 0; i < ITERS; ++i) {
        const int task = i * 256 + tid;
        const int r    = task / OCT;
        const int oct  = task % OCT;
        const u16x8 v = *reinterpret_cast<const u16x8*>(
            xb + (size_t)(e0 + r) * C + oct * 8);
        *reinterpret_cast<u16x8*>(&smem[0][r][oct * 8]) = v;
    }
    __syncthreads();
    mfma_seg(0, 0);
    __syncthreads();

    if constexpr (PAIRED) {
        // ---- Phase {s1,s3}: gather f1,f3; build sum and |diff| ----
#pragma unroll
        for (int i = 0; i < ITERS; ++i) {
            const int task = i * 256 + tid;
            const int r    = task / OCT;
            const int oct  = task % OCT;
            const u16x8 a = *reinterpret_cast<const u16x8*>(
                xb + (size_t)gis[r][0] * C + oct * 8);
            const u16x8 c = *reinterpret_cast<const u16x8*>(
                xb + (size_t)gis[r][2] * C + oct * 8);
            u16x8 vs, vd;
#pragma unroll
            for (int j = 0; j < 8; ++j) {
                const float fa = bfbits2f(a[j]);
                const float fc = bfbits2f(c[j]);
                vs[j] = f2bfbits(fa + fc);
                vd[j] = f2bfbits(fabsf(fa - fc));
            }
            *reinterpret_cast<u16x8*>(&smem[0][r][oct * 8]) = vs;
            *reinterpret_cast<u16x8*>(&smem[SLOTS - 1][r][oct * 8]) = vd;
        }
        __syncthreads();
        mfma_seg(0, 1);
        mfma_seg(SLOTS - 1, 3);
        __syncthreads();
        // ---- Phase {s2,s4}: gather f2,f4 ----
#pragma unroll
        for (int i = 0; i < ITERS; ++i) {
            const int task = i * 256 + tid;
            const int r    = task / OCT;
            const int oct  = task % OCT;
            const u16x8 a = *reinterpret_cast<const u16x8*>(
                xb + (size_t)gis[r][1] * C + oct * 8);
            const u16x8 c = *reinterpret_cast<const u16x8*>(
                xb + (size_t)gis[r][3] * C + oct * 8);
            u16x8 vs, vd;
#pragma unroll
            for (int j = 0; j < 8; ++j) {
                const float fa = bfbits2f(a[j]);
                const float fc = bfbits2f(c[j]);
                vs[j] = f2bfbits(fa + fc);
                vd[j] = f2bfbits(fabsf(fa - fc));
            }
            *reinterpret_cast<u16x8*>(&smem[0][r][oct * 8]) = vs;
            *reinterpret_cast<u16x8*>(&smem[SLOTS - 1][r][oct * 8]) = vd;
        }
        __syncthreads();
        mfma_seg(0, 2);
        mfma_seg(SLOTS - 1, 4);
    } else {
        // ---- C=256: single slot, one segment at a time ----
#pragma unroll
        for (int s = 1; s <= 4; ++s) {
            const int ia = (s == 1 || s == 3) ? 0 : 1;
#pragma unroll
            for (int i = 0; i < ITERS; ++i) {
                const int task = i * 256 + tid;
                const int r    = task / OCT;
                const int oct  = task % OCT;
                const u16x8 a = *reinterpret_cast<const u16x8*>(
                    xb + (size_t)gis[r][ia] * C + oct * 8);
                const u16x8 c = *reinterpret_cast<const u16x8*>(
                    xb + (size_t)gis[r][ia + 2] * C + oct * 8);
                u16x8 v;
#pragma unroll
                for (int j = 0; j < 8; ++j) {
                    const float fa = bfbits2f(a[j]);
                    const float fc = bfbits2f(c[j]);
                    v[j] = f2bfbits((s < 3) ? (fa + fc) : fabsf(fa - fc));
                }
                *reinterpret_cast<u16x8*>(&smem[0][r][oct * 8]) = v;
            }
            __syncthreads();
            mfma_seg(0, s);
            if (s != 4) __syncthreads();
        }
    }

    // ---- epilogue: bias + store (+ fused stats) ----
    const int ebase = e0 + wave * 16 + kq * 4;
    float ssum[NT], ssq[NT];
#pragma unroll
    for (int nt = 0; nt < NT; ++nt) { ssum[nt] = 0.f; ssq[nt] = 0.f; }
#pragma unroll
    for (int nt = 0; nt < NT; ++nt) {
        const int o = nt * 16 + m;
        if (o < OW) {
            const float bo = bias[o];
#pragma unroll
            for (int r = 0; r < 4; ++r) {
                const float z = acc[nt][r] + bo;
                out[((size_t)b * E + (ebase + r)) * OW + o] = f2bfbits(z);
                ssum[nt] += z; ssq[nt] += z * z;
            }
        }
    }

    if constexpr (STATS) {
        __shared__ float ls[4][2][O];
#pragma unroll
        for (int nt = 0; nt < NT; ++nt) {
            float s = ssum[nt], q = ssq[nt];
            s += __shfl_xor(s, 16); s += __shfl_xor(s, 32);
            q += __shfl_xor(q, 16); q += __shfl_xor(q, 32);
            if (kq == 0) { ls[wave][0][nt * 16 + m] = s; ls[wave][1][nt * 16 + m] = q; }
        }
        __syncthreads();
        if (tid < O) {
            const float S = ls[0][0][tid] + ls[1][0][tid] + ls[2][0][tid] + ls[3][0][tid];
            const float Q = ls[0][1][tid] + ls[1][1][tid] + ls[2][1][tid] + ls[3][1][tid];
            atomicAdd(&stats[((size_t)b * O + tid) * 2], S);
            atomicAdd(&stats[((size_t)b * O + tid) * 2 + 1], Q);
        }
    }
}

// VALU mesh_conv for C=8,O=8 (L2-resident rows): one e per thread.
template<int C, int O, bool STATS>
__global__ __launch_bounds__(256) void k_conv_small(
    const unsigned short* __restrict__ x, const int* __restrict__ gm,
    const float* __restrict__ Wt, const float* __restrict__ bias,
    unsigned short* __restrict__ out, float* __restrict__ stats, int E)
{
    static_assert(O == 8 && C % 8 == 0, "bad cfg");
    __shared__ float ls[2 * O];
    const int tid = threadIdx.x;
    if constexpr (STATS) {
        if (tid < 2 * O) ls[tid] = 0.f;
        __syncthreads();
    }
    const int b = blockIdx.y;
    const int e = blockIdx.x * 256 + tid;
    const unsigned short* xb = x + (size_t)b * E * C;
    const int4 gi = *reinterpret_cast<const int4*>(gm + 4 * (size_t)e);
    const unsigned short* rp[5] = {
        xb + (size_t)e * C, xb + (size_t)gi.x * C, xb + (size_t)gi.y * C,
        xb + (size_t)gi.z * C, xb + (size_t)gi.w * C };

    float acc[O];
#pragma unroll
    for (int o = 0; o < O; ++o) acc[o] = bias[o];

#pragma unroll
    for (int c = 0; c < C; c += 8) {
        u16x8 rv[5];
#pragma unroll
        for (int k = 0; k < 5; ++k) rv[k] = *reinterpret_cast<const u16x8*>(rp[k] + c);
#pragma unroll
        for (int cc = 0; cc < 8; ++cc) {
            const float x0 = bfbits2f(rv[0][cc]);
            const float f1 = bfbits2f(rv[1][cc]);
            const float f2 = bfbits2f(rv[2][cc]);
            const float f3 = bfbits2f(rv[3][cc]);
            const float f4 = bfbits2f(rv[4][cc]);
            const float gv[5] = { x0, f1 + f3, f2 + f4, fabsf(f1 - f3), fabsf(f2 - f4) };
            const float* wbase = Wt + (size_t)(c + cc) * 5 * O;
#pragma unroll
            for (int s = 0; s < 5; ++s)
#pragma unroll
                for (int o = 0; o < O; ++o)
                    acc[o] += gv[s] * wbase[s * O + o];
        }
    }

    u16x8 ov;
#pragma unroll
    for (int o = 0; o < O; ++o) ov[o] = f2bfbits(acc[o]);
    *reinterpret_cast<u16x8*>(out + ((size_t)b * E + e) * O) = ov;

    if constexpr (STATS) {
#pragma unroll
        for (int o = 0; o < O; ++o) {
            atomicAdd(&ls[o * 2], acc[o]);
            atomicAdd(&ls[o * 2 + 1], acc[o] * acc[o]);
        }
        __syncthreads();
        if (tid < 2 * O) atomicAdd(&stats[(size_t)b * 2 * O + tid], ls[tid]);
    }
}

// x1[b,e,o] = y[b, up[e], o] + skip[b, o, e]  -- LDS-tiled (coalesced skip reads)
template<int O>
__global__ __launch_bounds__(256) void k_unpool_skip(
    const unsigned short* __restrict__ y, const int* __restrict__ up,
    const float* __restrict__ skip, unsigned short* __restrict__ out,
    int Ein, int Eout)
{
    __shared__ float sk[O][65];
    const int b  = blockIdx.y;
    const int e0 = blockIdx.x * 64;
    const int t  = threadIdx.x;
    constexpr int L = O / 16;   // float4 loads per thread
#pragma unroll
    for (int i = 0; i < L; ++i) {
        const int flat = i * 256 + t;
        const int o = flat >> 4;
        const int el4 = (flat & 15) * 4;
        const float4 v = *reinterpret_cast<const float4*>(
            skip + ((size_t)b * O + o) * Eout + e0 + el4);
        sk[o][el4]     = v.x;
        sk[o][el4 + 1] = v.y;
        sk[o][el4 + 2] = v.z;
        sk[o][el4 + 3] = v.w;
    }
    __syncthreads();
    constexpr int OG  = O / 4;       // threads per e
    constexpr int EPP = 256 / OG;    // e's per pass
    const int o4  = (t % OG) * 4;
    const int elg = t / OG;
#pragma unroll
    for (int p = 0; p < 64 / EPP; ++p) {
        const int el = p * EPP + elg;
        const int e  = e0 + el;
        const int u  = up[e];
        const ushort4 yv = *reinterpret_cast<const ushort4*>(
            y + ((size_t)b * Ein + u) * O + o4);
        ushort4 ov;
        ov.x = f2bfbits(bfbits2f(yv.x) + sk[o4 + 0][el]);
        ov.y = f2bfbits(bfbits2f(yv.y) + sk[o4 + 1][el]);
        ov.z = f2bfbits(bfbits2f(yv.z) + sk[o4 + 2][el]);
        ov.w = f2bfbits(bfbits2f(yv.w) + sk[o4 + 3][el]);
        *reinterpret_cast<ushort4*>(out + ((size_t)b * Eout + e) * O + o4) = ov;
    }
}

// stats -> scale/shift
__global__ __launch_bounds__(256) void k_scale(
    const float* __restrict__ stats, float* __restrict__ ss, int BC, float invE)
{
    const int t = threadIdx.x;
    if (t < BC) {
        const float sum = stats[t * 2];
        const float sq  = stats[t * 2 + 1];
        const float m   = sum * invE;
        const float var = fmaxf(sq * invE - m * m, 0.f);
        const float sc  = rsqrtf(var + 1e-5f);
        ss[t * 2] = sc;
        ss[t * 2 + 1] = -m * sc;
    }
}

// in-place relu((x)*sc + sh), vectorized ushort8
template<int C>
__global__ __launch_bounds__(256) void k_norm_relu(
    unsigned short* __restrict__ x, const float* __restrict__ ss, int E)
{
    const int b = blockIdx.y;
    const size_t i8 = ((size_t)blockIdx.x * 256 + threadIdx.x) * 8;
    const int c0 = (int)(i8 % C);
    unsigned short* p = x + (size_t)b * E * C + i8;
    const u16x8 v = *reinterpret_cast<const u16x8*>(p);
    u16x8 r;
#pragma unroll
    for (int j = 0; j < 8; ++j) {
        const float sc = ss[(b * C + c0 + j) * 2];
        const float sh = ss[(b * C + c0 + j) * 2 + 1];
        r[j] = f2bfbits(fmaxf(bfbits2f(v[j]) * sc + sh, 0.f));
    }
    *reinterpret_cast<u16x8*>(p) = r;
}

// final: (B,E,8) bf16 -> norm+relu -> (B,8,E) fp32
__global__ __launch_bounds__(256) void k_final_out(
    const unsigned short* __restrict__ z, const float* __restrict__ ss,
    float* __restrict__ out, int E)
{
    const int b = blockIdx.y;
    const int idx = blockIdx.x * 256 + threadIdx.x;  // over 8*E
    const int o = idx / E;
    const int e = idx % E;
    const float sc = ss[((size_t)b * 8 + o) * 2];
    const float sh = ss[((size_t)b * 8 + o) * 2 + 1];
    const float v = bfbits2f(z[((size_t)b * E + e) * 8 + o]) * sc + sh;
    out[(size_t)b * 8 * E + idx] = fmaxf(v, 0.f);
}

extern "C" void kernel_launch(void* const* d_in, const int* in_sizes, int n_in,
                              void* d_out, int out_size, void* d_ws, size_t ws_size,
                              hipStream_t stream)
{
    (void)in_sizes; (void)n_in; (void)out_size; (void)ws_size;

    const float* fe = (const float*)d_in[0];
    const int* gemm0 = (const int*)d_in[4];
    const int* gemm1 = (const int*)d_in[5];
    const int* gemm2 = (const int*)d_in[6];
    const int* gemm3 = (const int*)d_in[7];
    const int* up0 = (const int*)d_in[8];
    const int* up1 = (const int*)d_in[9];
    const int* up2 = (const int*)d_in[10];
    const float* bup0 = (const float*)d_in[12];
    const float* bc0  = (const float*)d_in[14];
    const float* bup1 = (const float*)d_in[16];
    const float* bc1  = (const float*)d_in[18];
    const float* bup2 = (const float*)d_in[20];
    const float* bc2  = (const float*)d_in[22];
    const float* bupf = (const float*)d_in[24];
    const float* bcf  = (const float*)d_in[26];

    unsigned short* wsb = (unsigned short*)d_ws;
    const size_t NP = 8388608;  // 2*32768*128 = max activation elems
    unsigned short* P0 = wsb;
    unsigned short* P1 = wsb + NP;
    unsigned short* P2 = wsb + 2 * NP;
    unsigned short* Bp_up0 = wsb + 3 * NP;       // 5*256*128 = 163840
    unsigned short* Bp_c0  = Bp_up0 + 163840;    // 5*128*128 =  81920
    unsigned short* Bp_up1 = Bp_c0  + 81920;     // 5*128*64  =  40960
    unsigned short* Bp_c1  = Bp_up1 + 40960;     // 5*64*64   =  20480
    unsigned short* Bp_up2 = Bp_c1  + 20480;     // 5*64*32   =  10240
    unsigned short* Bp_c2  = Bp_up2 + 10240;     // 5*32*32   =   5120
    unsigned short* Bp_upf = Bp_c2  + 5120;      // 5*32*16   =   2560 (O padded 8->16)
    float* fls    = (float*)(Bp_upf + 2560);
    float* wt_cf  = fls;                  //  8*5*8 =  320
    float* stats0 = wt_cf  + 320;         // 2*128*2 = 512
    float* stats1 = stats0 + 512;         // 2*64*2  = 256
    float* stats2 = stats1 + 256;         // 2*32*2  = 128
    float* stats3 = stats2 + 128;         // 2*8*2   = 32
    float* ss0    = stats3 + 32;
    float* ss1    = ss0 + 512;
    float* ss2    = ss1 + 256;
    float* ss3    = ss2 + 128;

    hipMemsetAsync(stats0, 0, 928 * sizeof(float), stream);

    const dim3 blk(256);

    // input transpose: fe (2,256,16384) fp32 -> P0 (2,16384,256) bf16
    k_transpose_in<<<dim3(16384 / 64, 256 / 64, 2), blk, 0, stream>>>(fe, P0, 256, 16384);

    // weight packing
    k_prep_b<<<dim3(163840 / 256), blk, 0, stream>>>((const float*)d_in[11], Bp_up0, 256, 128, 128);
    k_prep_b<<<dim3(81920 / 256),  blk, 0, stream>>>((const float*)d_in[13], Bp_c0, 128, 128, 128);
    k_prep_b<<<dim3(40960 / 256),  blk, 0, stream>>>((const float*)d_in[15], Bp_up1, 128, 64, 64);
    k_prep_b<<<dim3(20480 / 256),  blk, 0, stream>>>((const float*)d_in[17], Bp_c1, 64, 64, 64);
    k_prep_b<<<dim3(10240 / 256),  blk, 0, stream>>>((const float*)d_in[19], Bp_up2, 64, 32, 32);
    k_prep_b<<<dim3(5120 / 256),   blk, 0, stream>>>((const float*)d_in[21], Bp_c2, 32, 32, 32);
    k_prep_b<<<dim3(2560 / 256),   blk, 0, stream>>>((const float*)d_in[23], Bp_upf, 32, 16, 8);
    k_prep_w<<<dim3((320 + 255) / 256), blk, 0, stream>>>((const float*)d_in[25], wt_cf, 8, 8);

    // ---- stage 0 ----
    k_conv_mfma<256, 128, false><<<dim3(16384 / 64, 2), blk, 0, stream>>>(P0, gemm0, Bp_up0, bup0, P1, nullptr, 16384);
    k_unpool_skip<128><<<dim3(32768 / 64, 2), blk, 0, stream>>>(P1, up0, (const float*)d_in[1], P2, 16384, 32768);
    k_conv_mfma<128, 128, true><<<dim3(32768 / 64, 2), blk, 0, stream>>>(P2, gemm1, Bp_c0, bc0, P0, stats0, 32768);
    k_scale<<<dim3(1), blk, 0, stream>>>(stats0, ss0, 256, 1.f / 32768.f);
    k_norm_relu<128><<<dim3(32768 * 128 / 2048, 2), blk, 0, stream>>>(P0, ss0, 32768);

    // ---- stage 1 ----
    k_conv_mfma<128, 64, false><<<dim3(32768 / 64, 2), blk, 0, stream>>>(P0, gemm1, Bp_up1, bup1, P1, nullptr, 32768);
    k_unpool_skip<64><<<dim3(65536 / 64, 2), blk, 0, stream>>>(P1, up1, (const float*)d_in[2], P2, 32768, 65536);
    k_conv_mfma<64, 64, true><<<dim3(65536 / 64, 2), blk, 0, stream>>>(P2, gemm2, Bp_c1, bc1, P0, stats1, 65536);
    k_scale<<<dim3(1), blk, 0, stream>>>(stats1, ss1, 128, 1.f / 65536.f);
    k_norm_relu<64><<<dim3(65536 * 64 / 2048, 2), blk, 0, stream>>>(P0, ss1, 65536);

    // ---- stage 2 ----
    k_conv_mfma<64, 32, false><<<dim3(65536 / 64, 2), blk, 0, stream>>>(P0, gemm2, Bp_up2, bup2, P1, nullptr, 65536);
    k_unpool_skip<32><<<dim3(131072 / 64, 2), blk, 0, stream>>>(P1, up2, (const float*)d_in[3], P2, 65536, 131072);
    k_conv_mfma<32, 32, true><<<dim3(131072 / 64, 2), blk, 0, stream>>>(P2, gemm3, Bp_c2, bc2, P0, stats2, 131072);
    k_scale<<<dim3(1), blk, 0, stream>>>(stats2, ss2, 64, 1.f / 131072.f);
    k_norm_relu<32><<<dim3(131072 * 32 / 2048, 2), blk, 0, stream>>>(P0, ss2, 131072);

    // ---- final ----
    k_conv_mfma<32, 16, false, 8><<<dim3(131072 / 64, 2), blk, 0, stream>>>(P0, gemm3, Bp_upf, bupf, P1, nullptr, 131072);
    k_conv_small<8, 8, true><<<dim3(131072 / 256, 2), blk, 0, stream>>>(P1, gemm3, wt_cf, bcf, P2, stats3, 131072);
    k_scale<<<dim3(1), blk, 0, stream>>>(stats3, ss3, 16, 1.f / 131072.f);
    k_final_out<<<dim3(8 * 131072 / 256, 2), blk, 0, stream>>>(P2, ss3, (float*)d_out, 131072);
}

// Round 7
// 723.470 us; speedup vs baseline: 1.1912x; 1.0271x over previous
//
#include <hip/hip_runtime.h>
#include <hip/hip_bf16.h>
#include <cstdint>
#include <cstddef>

// ---------------------------------------------------------------------------
// MeshDecoder pipeline, round 7.
// bf16 activations (B,E,C). Convs: s0 A-frags direct from global (coalesced);
// gather segments cooperatively staged to LDS with ALL of a block's gather
// loads issued in one phase (max MLP; R6 was 2 loads/thread per barrier -> 
// Little's-law-starved at 446 GB/s). Stats fused in epilogues.
// ---------------------------------------------------------------------------

typedef short s16x8 __attribute__((ext_vector_type(8)));
typedef unsigned short u16x8 __attribute__((ext_vector_type(8)));
typedef float f32x4 __attribute__((ext_vector_type(4)));

__device__ __forceinline__ float bfbits2f(unsigned short u) {
    unsigned int x = ((unsigned int)u) << 16;
    float f; __builtin_memcpy(&f, &x, sizeof(f)); return f;
}
__device__ __forceinline__ unsigned short f2bfbits(float f) {
    __hip_bfloat16 h = __float2bfloat16(f);
    unsigned short u; __builtin_memcpy(&u, &h, sizeof(u)); return u;
}

// (B,C,E) fp32 -> (B,E,C) bf16 tiled transpose
__global__ __launch_bounds__(256) void k_transpose_in(
    const float* __restrict__ in, unsigned short* __restrict__ out, int C, int E)
{
    __shared__ float tile[64][65];
    const int e0 = blockIdx.x * 64;
    const int c0 = blockIdx.y * 64;
    const int b  = blockIdx.z;
    const float* inb = in + (size_t)b * C * E;
    const int l = threadIdx.x % 64;
    const int g = threadIdx.x / 64;
#pragma unroll
    for (int i = 0; i < 16; ++i) {
        const int c = i * 4 + g;
        tile[c][l] = inb[(size_t)(c0 + c) * E + e0 + l];
    }
    __syncthreads();
    unsigned short* outb = out + (size_t)b * E * C;
#pragma unroll
    for (int i = 0; i < 16; ++i) {
        const int e = i * 4 + g;
        outb[(size_t)(e0 + e) * C + c0 + l] = f2bfbits(tile[l][e]);
    }
}

// W (O,C,5) fp32 -> B-fragment-packed bf16: Bp[((kk*OP)+o)*8 + j], k=kk*8+j=s*C+c
__global__ __launch_bounds__(256) void k_prep_b(
    const float* __restrict__ W, unsigned short* __restrict__ Bp, int C, int OP, int OL)
{
    const int p = blockIdx.x * 256 + threadIdx.x;
    const int total = 5 * C * OP;
    if (p >= total) return;
    const int j = p & 7;
    const int t = p >> 3;
    const int o = t % OP;
    const int kk = t / OP;
    const int k = kk * 8 + j;
    const int s = k / C;
    const int c = k - s * C;
    Bp[p] = (o < OL) ? f2bfbits(W[((size_t)o * C + c) * 5 + s]) : (unsigned short)0;
}

// W (O,C,5) fp32 -> W_T[(c*5+s)*O + o] fp32 (VALU-path weights)
__global__ __launch_bounds__(256) void k_prep_w(
    const float* __restrict__ W, float* __restrict__ Wt, int C, int O)
{
    const int idx = blockIdx.x * 256 + threadIdx.x;
    const int total = C * 5 * O;
    if (idx >= total) return;
    const int k = idx / O;
    const int o = idx % O;
    const int c = k / 5;
    const int s = k - 5 * c;
    Wt[idx] = W[((size_t)o * C + c) * 5 + s];
}

// LDS-staged MFMA mesh_conv. Block = 64 e-rows, 256 threads (4 waves).
// s0 A-frags come straight from global (coalesced). Gather segments staged:
//   C<=64 : 4 slots, single phase (all gathers in flight at once)
//   C==128: 2 slots, 2 phases ({f1,f3} then {f2,f4})
//   C==256: 1 slot, 4 phases (reload pairs; E is small so it's cheap)
template<int C, int O, bool STATS, int OW = O>
__global__ __launch_bounds__(256) void k_conv_mfma(
    const unsigned short* __restrict__ x, const int* __restrict__ gm,
    const unsigned short* __restrict__ Bp, const float* __restrict__ bias,
    unsigned short* __restrict__ out, float* __restrict__ stats, int E)
{
    constexpr int NT    = O / 16;
    constexpr int ITS   = C / 32;        // 16x16x32 k-steps per segment
    constexpr int OCT   = C / 8;         // 16B octets per row per segment
    constexpr int ITERS = (64 * OCT) / 256;
    constexpr int PAD   = 8;
    constexpr int RW    = C + PAD;
    constexpr int NSLOT = (C <= 64) ? 4 : (C == 128) ? 2 : 1;
    static_assert(C % 32 == 0 && O % 16 == 0, "bad cfg");

    __shared__ unsigned short smem[NSLOT][64][RW];
    __shared__ int gis[64][4];

    const int tid  = threadIdx.x;
    const int wave = tid >> 6;
    const int lane = tid & 63;
    const int m    = lane & 15;
    const int kq   = lane >> 4;
    const int b    = blockIdx.y;
    const int e0   = blockIdx.x * 64;
    const unsigned short* xb = x + (size_t)b * E * C;
    const s16x8* Bp8 = reinterpret_cast<const s16x8*>(Bp);

    if (tid < 64)
        *reinterpret_cast<int4*>(gis[tid]) =
            *reinterpret_cast<const int4*>(gm + 4 * (size_t)(e0 + tid));
    __syncthreads();

    // s=0 A fragments directly from global (coalesced 16B/lane)
    s16x8 a0[ITS];
    {
        const unsigned short* myrow = xb + (size_t)(e0 + wave * 16 + m) * C;
#pragma unroll
        for (int it = 0; it < ITS; ++it)
            a0[it] = *reinterpret_cast<const s16x8*>(myrow + it * 32 + kq * 8);
    }

    f32x4 acc[NT];
#pragma unroll
    for (int nt = 0; nt < NT; ++nt) acc[nt] = (f32x4){0.f, 0.f, 0.f, 0.f};

    auto mfma_own = [&]() {
#pragma unroll
        for (int it = 0; it < ITS; ++it) {
            const int kkb = it * 4 + kq;   // s=0
#pragma unroll
            for (int nt = 0; nt < NT; ++nt)
                acc[nt] = __builtin_amdgcn_mfma_f32_16x16x32_bf16(
                    a0[it], Bp8[(size_t)kkb * O + nt * 16 + m], acc[nt], 0, 0, 0);
        }
    };
    auto mfma_seg = [&](int slot, int s) {
#pragma unroll
        for (int it = 0; it < ITS; ++it) {
            const s16x8 afrag = *reinterpret_cast<const s16x8*>(
                &smem[slot][wave * 16 + m][it * 32 + kq * 8]);
            const int kkb = s * OCT + it * 4 + kq;
#pragma unroll
            for (int nt = 0; nt < NT; ++nt)
                acc[nt] = __builtin_amdgcn_mfma_f32_16x16x32_bf16(
                    afrag, Bp8[(size_t)kkb * O + nt * 16 + m], acc[nt], 0, 0, 0);
        }
    };

    if constexpr (C <= 64) {
        // single staging phase: all 4 gather segments, 4*ITERS loads in flight
#pragma unroll
        for (int i = 0; i < ITERS; ++i) {
            const int task = i * 256 + tid;
            const int r    = task / OCT;
            const int oct  = task % OCT;
            const int off  = oct * 8;
            const int4 gi = *reinterpret_cast<const int4*>(gis[r]);
            const u16x8 f1 = *reinterpret_cast<const u16x8*>(xb + (size_t)gi.x * C + off);
            const u16x8 f3 = *reinterpret_cast<const u16x8*>(xb + (size_t)gi.z * C + off);
            const u16x8 f2 = *reinterpret_cast<const u16x8*>(xb + (size_t)gi.y * C + off);
            const u16x8 f4 = *reinterpret_cast<const u16x8*>(xb + (size_t)gi.w * C + off);
            u16x8 vs13, vd13, vs24, vd24;
#pragma unroll
            for (int j = 0; j < 8; ++j) {
                const float a1 = bfbits2f(f1[j]), a3 = bfbits2f(f3[j]);
                const float a2 = bfbits2f(f2[j]), a4 = bfbits2f(f4[j]);
                vs13[j] = f2bfbits(a1 + a3);
                vd13[j] = f2bfbits(fabsf(a1 - a3));
                vs24[j] = f2bfbits(a2 + a4);
                vd24[j] = f2bfbits(fabsf(a2 - a4));
            }
            *reinterpret_cast<u16x8*>(&smem[0][r][off]) = vs13;
            *reinterpret_cast<u16x8*>(&smem[1][r][off]) = vd13;
            *reinterpret_cast<u16x8*>(&smem[2][r][off]) = vs24;
            *reinterpret_cast<u16x8*>(&smem[3][r][off]) = vd24;
        }
        __syncthreads();
        mfma_own();
        mfma_seg(0, 1); mfma_seg(1, 3); mfma_seg(2, 2); mfma_seg(3, 4);
    } else if constexpr (C == 128) {
        // phase A: {f1,f3}
#pragma unroll
        for (int i = 0; i < ITERS; ++i) {
            const int task = i * 256 + tid;
            const int r = task / OCT, oct = task % OCT, off = oct * 8;
            const int4 gi = *reinterpret_cast<const int4*>(gis[r]);
            const u16x8 f1 = *reinterpret_cast<const u16x8*>(xb + (size_t)gi.x * C + off);
            const u16x8 f3 = *reinterpret_cast<const u16x8*>(xb + (size_t)gi.z * C + off);
            u16x8 vs, vd;
#pragma unroll
            for (int j = 0; j < 8; ++j) {
                const float a1 = bfbits2f(f1[j]), a3 = bfbits2f(f3[j]);
                vs[j] = f2bfbits(a1 + a3);
                vd[j] = f2bfbits(fabsf(a1 - a3));
            }
            *reinterpret_cast<u16x8*>(&smem[0][r][off]) = vs;
            *reinterpret_cast<u16x8*>(&smem[1][r][off]) = vd;
        }
        __syncthreads();
        mfma_own();
        mfma_seg(0, 1); mfma_seg(1, 3);
        __syncthreads();
        // phase B: {f2,f4}
#pragma unroll
        for (int i = 0; i < ITERS; ++i) {
            const int task = i * 256 + tid;
            const int r = task / OCT, oct = task % OCT, off = oct * 8;
            const int4 gi = *reinterpret_cast<const int4*>(gis[r]);
            const u16x8 f2 = *reinterpret_cast<const u16x8*>(xb + (size_t)gi.y * C + off);
            const u16x8 f4 = *reinterpret_cast<const u16x8*>(xb + (size_t)gi.w * C + off);
            u16x8 vs, vd;
#pragma unroll
            for (int j = 0; j < 8; ++j) {
                const float a2 = bfbits2f(f2[j]), a4 = bfbits2f(f4[j]);
                vs[j] = f2bfbits(a2 + a4);
                vd[j] = f2bfbits(fabsf(a2 - a4));
            }
            *reinterpret_cast<u16x8*>(&smem[0][r][off]) = vs;
            *reinterpret_cast<u16x8*>(&smem[1][r][off]) = vd;
        }
        __syncthreads();
        mfma_seg(0, 2); mfma_seg(1, 4);
    } else {
        // C==256: single slot, 4 sequential phases
#pragma unroll
        for (int s = 1; s <= 4; ++s) {
            const int ia = (s == 1 || s == 3) ? 0 : 1;
#pragma unroll
            for (int i = 0; i < ITERS; ++i) {
                const int task = i * 256 + tid;
                const int r = task / OCT, oct = task % OCT, off = oct * 8;
                const int4 gi = *reinterpret_cast<const int4*>(gis[r]);
                const int ra = (ia == 0) ? gi.x : gi.y;
                const int rc = (ia == 0) ? gi.z : gi.w;
                const u16x8 a = *reinterpret_cast<const u16x8*>(xb + (size_t)ra * C + off);
                const u16x8 c = *reinterpret_cast<const u16x8*>(xb + (size_t)rc * C + off);
                u16x8 v;
#pragma unroll
                for (int j = 0; j < 8; ++j) {
                    const float fa = bfbits2f(a[j]);
                    const float fc = bfbits2f(c[j]);
                    v[j] = f2bfbits((s < 3) ? (fa + fc) : fabsf(fa - fc));
                }
                *reinterpret_cast<u16x8*>(&smem[0][r][off]) = v;
            }
            __syncthreads();
            if (s == 1) mfma_own();
            mfma_seg(0, s);
            if (s != 4) __syncthreads();
        }
    }

    // ---- epilogue: bias + store (+ fused stats) ----
    const int ebase = e0 + wave * 16 + kq * 4;
    float ssum[NT], ssq[NT];
#pragma unroll
    for (int nt = 0; nt < NT; ++nt) { ssum[nt] = 0.f; ssq[nt] = 0.f; }
#pragma unroll
    for (int nt = 0; nt < NT; ++nt) {
        const int o = nt * 16 + m;
        if (o < OW) {
            const float bo = bias[o];
#pragma unroll
            for (int r = 0; r < 4; ++r) {
                const float z = acc[nt][r] + bo;
                out[((size_t)b * E + (ebase + r)) * OW + o] = f2bfbits(z);
                ssum[nt] += z; ssq[nt] += z * z;
            }
        }
    }

    if constexpr (STATS) {
        __shared__ float ls[4][2][O];
#pragma unroll
        for (int nt = 0; nt < NT; ++nt) {
            float s = ssum[nt], q = ssq[nt];
            s += __shfl_xor(s, 16); s += __shfl_xor(s, 32);
            q += __shfl_xor(q, 16); q += __shfl_xor(q, 32);
            if (kq == 0) { ls[wave][0][nt * 16 + m] = s; ls[wave][1][nt * 16 + m] = q; }
        }
        __syncthreads();
        if (tid < O) {
            const float S = ls[0][0][tid] + ls[1][0][tid] + ls[2][0][tid] + ls[3][0][tid];
            const float Q = ls[0][1][tid] + ls[1][1][tid] + ls[2][1][tid] + ls[3][1][tid];
            atomicAdd(&stats[((size_t)b * O + tid) * 2], S);
            atomicAdd(&stats[((size_t)b * O + tid) * 2 + 1], Q);
        }
    }
}

// VALU mesh_conv for C=8,O=8: one e per thread.
template<int C, int O, bool STATS>
__global__ __launch_bounds__(256) void k_conv_small(
    const unsigned short* __restrict__ x, const int* __restrict__ gm,
    const float* __restrict__ Wt, const float* __restrict__ bias,
    unsigned short* __restrict__ out, float* __restrict__ stats, int E)
{
    static_assert(O == 8 && C % 8 == 0, "bad cfg");
    __shared__ float ls[2 * O];
    const int tid = threadIdx.x;
    if constexpr (STATS) {
        if (tid < 2 * O) ls[tid] = 0.f;
        __syncthreads();
    }
    const int b = blockIdx.y;
    const int e = blockIdx.x * 256 + tid;
    const unsigned short* xb = x + (size_t)b * E * C;
    const int4 gi = *reinterpret_cast<const int4*>(gm + 4 * (size_t)e);
    const unsigned short* rp[5] = {
        xb + (size_t)e * C, xb + (size_t)gi.x * C, xb + (size_t)gi.y * C,
        xb + (size_t)gi.z * C, xb + (size_t)gi.w * C };

    float acc[O];
#pragma unroll
    for (int o = 0; o < O; ++o) acc[o] = bias[o];

#pragma unroll
    for (int c = 0; c < C; c += 8) {
        u16x8 rv[5];
#pragma unroll
        for (int k = 0; k < 5; ++k) rv[k] = *reinterpret_cast<const u16x8*>(rp[k] + c);
#pragma unroll
        for (int cc = 0; cc < 8; ++cc) {
            const float x0 = bfbits2f(rv[0][cc]);
            const float f1 = bfbits2f(rv[1][cc]);
            const float f2 = bfbits2f(rv[2][cc]);
            const float f3 = bfbits2f(rv[3][cc]);
            const float f4 = bfbits2f(rv[4][cc]);
            const float gv[5] = { x0, f1 + f3, f2 + f4, fabsf(f1 - f3), fabsf(f2 - f4) };
            const float* wbase = Wt + (size_t)(c + cc) * 5 * O;
#pragma unroll
            for (int s = 0; s < 5; ++s)
#pragma unroll
                for (int o = 0; o < O; ++o)
                    acc[o] += gv[s] * wbase[s * O + o];
        }
    }

    u16x8 ov;
#pragma unroll
    for (int o = 0; o < O; ++o) ov[o] = f2bfbits(acc[o]);
    *reinterpret_cast<u16x8*>(out + ((size_t)b * E + e) * O) = ov;

    if constexpr (STATS) {
#pragma unroll
        for (int o = 0; o < O; ++o) {
            atomicAdd(&ls[o * 2], acc[o]);
            atomicAdd(&ls[o * 2 + 1], acc[o] * acc[o]);
        }
        __syncthreads();
        if (tid < 2 * O) atomicAdd(&stats[(size_t)b * 2 * O + tid], ls[tid]);
    }
}

// x1[b,e,o] = y[b, up[e], o] + skip[b, o, e]  -- LDS-tiled (coalesced skip reads)
template<int O>
__global__ __launch_bounds__(256) void k_unpool_skip(
    const unsigned short* __restrict__ y, const int* __restrict__ up,
    const float* __restrict__ skip, unsigned short* __restrict__ out,
    int Ein, int Eout)
{
    __shared__ float sk[O][65];
    const int b  = blockIdx.y;
    const int e0 = blockIdx.x * 64;
    const int t  = threadIdx.x;
    constexpr int L = O / 16;   // float4 loads per thread
#pragma unroll
    for (int i = 0; i < L; ++i) {
        const int flat = i * 256 + t;
        const int o = flat >> 4;
        const int el4 = (flat & 15) * 4;
        const float4 v = *reinterpret_cast<const float4*>(
            skip + ((size_t)b * O + o) * Eout + e0 + el4);
        sk[o][el4]     = v.x;
        sk[o][el4 + 1] = v.y;
        sk[o][el4 + 2] = v.z;
        sk[o][el4 + 3] = v.w;
    }
    __syncthreads();
    constexpr int OG  = O / 4;       // threads per e
    constexpr int EPP = 256 / OG;    // e's per pass
    const int o4  = (t % OG) * 4;
    const int elg = t / OG;
#pragma unroll
    for (int p = 0; p < 64 / EPP; ++p) {
        const int el = p * EPP + elg;
        const int e  = e0 + el;
        const int u  = up[e];
        const ushort4 yv = *reinterpret_cast<const ushort4*>(
            y + ((size_t)b * Ein + u) * O + o4);
        ushort4 ov;
        ov.x = f2bfbits(bfbits2f(yv.x) + sk[o4 + 0][el]);
        ov.y = f2bfbits(bfbits2f(yv.y) + sk[o4 + 1][el]);
        ov.z = f2bfbits(bfbits2f(yv.z) + sk[o4 + 2][el]);
        ov.w = f2bfbits(bfbits2f(yv.w) + sk[o4 + 3][el]);
        *reinterpret_cast<ushort4*>(out + ((size_t)b * Eout + e) * O + o4) = ov;
    }
}

// stats -> scale/shift
__global__ __launch_bounds__(256) void k_scale(
    const float* __restrict__ stats, float* __restrict__ ss, int BC, float invE)
{
    const int t = threadIdx.x;
    if (t < BC) {
        const float sum = stats[t * 2];
        const float sq  = stats[t * 2 + 1];
        const float m   = sum * invE;
        const float var = fmaxf(sq * invE - m * m, 0.f);
        const float sc  = rsqrtf(var + 1e-5f);
        ss[t * 2] = sc;
        ss[t * 2 + 1] = -m * sc;
    }
}

// in-place relu((x)*sc + sh), vectorized ushort8
template<int C>
__global__ __launch_bounds__(256) void k_norm_relu(
    unsigned short* __restrict__ x, const float* __restrict__ ss, int E)
{
    const int b = blockIdx.y;
    const size_t i8 = ((size_t)blockIdx.x * 256 + threadIdx.x) * 8;
    const int c0 = (int)(i8 % C);
    unsigned short* p = x + (size_t)b * E * C + i8;
    const u16x8 v = *reinterpret_cast<const u16x8*>(p);
    u16x8 r;
#pragma unroll
    for (int j = 0; j < 8; ++j) {
        const float sc = ss[(b * C + c0 + j) * 2];
        const float sh = ss[(b * C + c0 + j) * 2 + 1];
        r[j] = f2bfbits(fmaxf(bfbits2f(v[j]) * sc + sh, 0.f));
    }
    *reinterpret_cast<u16x8*>(p) = r;
}

// final: (B,E,8) bf16 -> norm+relu -> (B,8,E) fp32
__global__ __launch_bounds__(256) void k_final_out(
    const unsigned short* __restrict__ z, const float* __restrict__ ss,
    float* __restrict__ out, int E)
{
    const int b = blockIdx.y;
    const int idx = blockIdx.x * 256 + threadIdx.x;  // over 8*E
    const int o = idx / E;
    const int e = idx % E;
    const float sc = ss[((size_t)b * 8 + o) * 2];
    const float sh = ss[((size_t)b * 8 + o) * 2 + 1];
    const float v = bfbits2f(z[((size_t)b * E + e) * 8 + o]) * sc + sh;
    out[(size_t)b * 8 * E + idx] = fmaxf(v, 0.f);
}

extern "C" void kernel_launch(void* const* d_in, const int* in_sizes, int n_in,
                              void* d_out, int out_size, void* d_ws, size_t ws_size,
                              hipStream_t stream)
{
    (void)in_sizes; (void)n_in; (void)out_size; (void)ws_size;

    const float* fe = (const float*)d_in[0];
    const int* gemm0 = (const int*)d_in[4];
    const int* gemm1 = (const int*)d_in[5];
    const int* gemm2 = (const int*)d_in[6];
    const int* gemm3 = (const int*)d_in[7];
    const int* up0 = (const int*)d_in[8];
    const int* up1 = (const int*)d_in[9];
    const int* up2 = (const int*)d_in[10];
    const float* bup0 = (const float*)d_in[12];
    const float* bc0  = (const float*)d_in[14];
    const float* bup1 = (const float*)d_in[16];
    const float* bc1  = (const float*)d_in[18];
    const float* bup2 = (const float*)d_in[20];
    const float* bc2  = (const float*)d_in[22];
    const float* bupf = (const float*)d_in[24];
    const float* bcf  = (const float*)d_in[26];

    unsigned short* wsb = (unsigned short*)d_ws;
    const size_t NP = 8388608;  // 2*32768*128 = max activation elems
    unsigned short* P0 = wsb;
    unsigned short* P1 = wsb + NP;
    unsigned short* P2 = wsb + 2 * NP;
    unsigned short* Bp_up0 = wsb + 3 * NP;       // 5*256*128 = 163840
    unsigned short* Bp_c0  = Bp_up0 + 163840;    // 5*128*128 =  81920
    unsigned short* Bp_up1 = Bp_c0  + 81920;     // 5*128*64  =  40960
    unsigned short* Bp_c1  = Bp_up1 + 40960;     // 5*64*64   =  20480
    unsigned short* Bp_up2 = Bp_c1  + 20480;     // 5*64*32   =  10240
    unsigned short* Bp_c2  = Bp_up2 + 10240;     // 5*32*32   =   5120
    unsigned short* Bp_upf = Bp_c2  + 5120;      // 5*32*16   =   2560 (O padded 8->16)
    float* fls    = (float*)(Bp_upf + 2560);
    float* wt_cf  = fls;                  //  8*5*8 =  320
    float* stats0 = wt_cf  + 320;         // 2*128*2 = 512
    float* stats1 = stats0 + 512;         // 2*64*2  = 256
    float* stats2 = stats1 + 256;         // 2*32*2  = 128
    float* stats3 = stats2 + 128;         // 2*8*2   = 32
    float* ss0    = stats3 + 32;
    float* ss1    = ss0 + 512;
    float* ss2    = ss1 + 256;
    float* ss3    = ss2 + 128;

    hipMemsetAsync(stats0, 0, 928 * sizeof(float), stream);

    const dim3 blk(256);

    // input transpose: fe (2,256,16384) fp32 -> P0 (2,16384,256) bf16
    k_transpose_in<<<dim3(16384 / 64, 256 / 64, 2), blk, 0, stream>>>(fe, P0, 256, 16384);

    // weight packing
    k_prep_b<<<dim3(163840 / 256), blk, 0, stream>>>((const float*)d_in[11], Bp_up0, 256, 128, 128);
    k_prep_b<<<dim3(81920 / 256),  blk, 0, stream>>>((const float*)d_in[13], Bp_c0, 128, 128, 128);
    k_prep_b<<<dim3(40960 / 256),  blk, 0, stream>>>((const float*)d_in[15], Bp_up1, 128, 64, 64);
    k_prep_b<<<dim3(20480 / 256),  blk, 0, stream>>>((const float*)d_in[17], Bp_c1, 64, 64, 64);
    k_prep_b<<<dim3(10240 / 256),  blk, 0, stream>>>((const float*)d_in[19], Bp_up2, 64, 32, 32);
    k_prep_b<<<dim3(5120 / 256),   blk, 0, stream>>>((const float*)d_in[21], Bp_c2, 32, 32, 32);
    k_prep_b<<<dim3(2560 / 256),   blk, 0, stream>>>((const float*)d_in[23], Bp_upf, 32, 16, 8);
    k_prep_w<<<dim3((320 + 255) / 256), blk, 0, stream>>>((const float*)d_in[25], wt_cf, 8, 8);

    // ---- stage 0 ----
    k_conv_mfma<256, 128, false><<<dim3(16384 / 64, 2), blk, 0, stream>>>(P0, gemm0, Bp_up0, bup0, P1, nullptr, 16384);
    k_unpool_skip<128><<<dim3(32768 / 64, 2), blk, 0, stream>>>(P1, up0, (const float*)d_in[1], P2, 16384, 32768);
    k_conv_mfma<128, 128, true><<<dim3(32768 / 64, 2), blk, 0, stream>>>(P2, gemm1, Bp_c0, bc0, P0, stats0, 32768);
    k_scale<<<dim3(1), blk, 0, stream>>>(stats0, ss0, 256, 1.f / 32768.f);
    k_norm_relu<128><<<dim3(32768 * 128 / 2048, 2), blk, 0, stream>>>(P0, ss0, 32768);

    // ---- stage 1 ----
    k_conv_mfma<128, 64, false><<<dim3(32768 / 64, 2), blk, 0, stream>>>(P0, gemm1, Bp_up1, bup1, P1, nullptr, 32768);
    k_unpool_skip<64><<<dim3(65536 / 64, 2), blk, 0, stream>>>(P1, up1, (const float*)d_in[2], P2, 32768, 65536);
    k_conv_mfma<64, 64, true><<<dim3(65536 / 64, 2), blk, 0, stream>>>(P2, gemm2, Bp_c1, bc1, P0, stats1, 65536);
    k_scale<<<dim3(1), blk, 0, stream>>>(stats1, ss1, 128, 1.f / 65536.f);
    k_norm_relu<64><<<dim3(65536 * 64 / 2048, 2), blk, 0, stream>>>(P0, ss1, 65536);

    // ---- stage 2 ----
    k_conv_mfma<64, 32, false><<<dim3(65536 / 64, 2), blk, 0, stream>>>(P0, gemm2, Bp_up2, bup2, P1, nullptr, 65536);
    k_unpool_skip<32><<<dim3(131072 / 64, 2), blk, 0, stream>>>(P1, up2, (const float*)d_in[3], P2, 65536, 131072);
    k_conv_mfma<32, 32, true><<<dim3(131072 / 64, 2), blk, 0, stream>>>(P2, gemm3, Bp_c2, bc2, P0, stats2, 131072);
    k_scale<<<dim3(1), blk, 0, stream>>>(stats2, ss2, 64, 1.f / 131072.f);
    k_norm_relu<32><<<dim3(131072 * 32 / 2048, 2), blk, 0, stream>>>(P0, ss2, 131072);

    // ---- final ----
    k_conv_mfma<32, 16, false, 8><<<dim3(131072 / 64, 2), blk, 0, stream>>>(P0, gemm3, Bp_upf, bupf, P1, nullptr, 131072);
    k_conv_small<8, 8, true><<<dim3(131072 / 256, 2), blk, 0, stream>>>(P1, gemm3, wt_cf, bcf, P2, stats3, 131072);
    k_scale<<<dim3(1), blk, 0, stream>>>(stats3, ss3, 16, 1.f / 131072.f);
    k_final_out<<<dim3(8 * 131072 / 256, 2), blk, 0, stream>>>(P2, ss3, (float*)d_out, 131072);
}